// Round 7
// baseline (130.050 us; speedup 1.0000x reference)
//
#include <hip/hip_runtime.h>

#define BATCH 2048
#define NNEI 64
#define IN_DIM 80
#define EMBED 256
#define NCLS 5
#define NMODES 20
#define NROWS (BATCH * NNEI)   // 131072
#define NEXP (NCLS + 1)        // 6 neighbor experts
#define TM 16                  // rows per MFMA tile
#define NTILES_MAX 8208        // >= 8192 + 6
#define GRIDB 768              // nei_gemm2 blocks (3/CU), 128 per class
#define TILE_SH 3072           // shorts per packed tile (3 ks * 2 part * 64 lane * 8)

typedef __attribute__((ext_vector_type(8))) short bf16x8;
typedef __attribute__((ext_vector_type(4))) float f32x4;
typedef __attribute__((ext_vector_type(4))) int i32x4;
typedef __attribute__((ext_vector_type(2))) int i32x2;

__device__ inline unsigned short bf16_rne(float f) {
    unsigned u = __builtin_bit_cast(unsigned, f);
    unsigned r = (u + 0x7fffu + ((u >> 16) & 1u)) >> 16;
    return (unsigned short)r;
}
__device__ inline float bf16_to_f(unsigned short h) {
    unsigned u = ((unsigned)h) << 16;
    return __builtin_bit_cast(float, u);
}

// ---------------- K1: bin rows by label (per-class region c*NROWS) ----
__global__ void bin_rows(const int* __restrict__ nei_labels,
                         int* __restrict__ counts, int* __restrict__ lists) {
    __shared__ int lc[NEXP], lb[NEXP];
    int t = threadIdx.x;
    if (t < NEXP) lc[t] = 0;
    __syncthreads();
    int r = blockIdx.x * 256 + t;
    int c = nei_labels[r];
    int lpos = atomicAdd(&lc[c], 1);
    __syncthreads();
    if (t < NEXP) lb[t] = atomicAdd(&counts[t], lc[t]);
    __syncthreads();
    lists[(size_t)c * NROWS + lb[c] + lpos] = r;
}

// ---------------- K1b: tile-offset scan ----------------
__global__ void scan_tiles(const int* __restrict__ counts, int* __restrict__ tileoff) {
    int s = 0;
    for (int c = 0; c < NEXP; ++c) { tileoff[c] = s; s += (counts[c] + TM - 1) / TM; }
    tileoff[NEXP] = s;
}

// ---------------- K2: pack tiles — gather+recip+hi/lo split, fragment-ordered ----
// packbuf[tile]: [ks(3)][part(2)][lane(64)][8 bf16]; k = ks*32 + (lane>>4)*8 + j,
// row = lane&15. k>=80 slots zeroed. Padded rows (gi>=cnt) zeroed.
__global__ void pack_tiles(const float* __restrict__ neis,
                           const int* __restrict__ counts, const int* __restrict__ tileoff,
                           const int* __restrict__ lists,
                           unsigned short* __restrict__ packbuf) {
    int bt = blockIdx.x;
    int c = -1;
    #pragma unroll
    for (int i = 0; i < NEXP; ++i)
        if (bt >= tileoff[i] && bt < tileoff[i + 1]) c = i;
    if (c < 0) return;
    int lt = bt - tileoff[c];
    int cnt = counts[c];
    const int* mylist = lists + (size_t)c * NROWS;
    unsigned short* tb = packbuf + (size_t)bt * TILE_SH;
    int t = threadIdx.x;

    // zero k>=80 fragment slots (ks=2, lanes 32..63, both parts): 64 x 16B
    if (t < 64) {
        int part = t >> 5, lane = 32 + (t & 31);
        *reinterpret_cast<i32x4*>(tb + 2 * 1024 + part * 512 + lane * 8) = (i32x4){0, 0, 0, 0};
    }

    for (int f = t; f < 320; f += 256) {        // 16 rows x 20 quads
        int row = f / 20, q = f - row * 20;
        int gi = lt * TM + row;
        int ks = q >> 3, lg = (q >> 1) & 3, half = q & 1;
        unsigned short* dhi = tb + ks * 1024 + (row + (lg << 4)) * 8 + half * 4;
        unsigned short hv[4] __attribute__((aligned(8)));
        unsigned short lv[4] __attribute__((aligned(8)));
        if (gi < cnt) {
            int rid = mylist[gi];
            float4 v = *reinterpret_cast<const float4*>(neis + (size_t)rid * IN_DIM + q * 4);
            float vv[4] = {v.x, v.y, v.z, v.w};
            #pragma unroll
            for (int j = 0; j < 4; ++j) {
                float d = (vv[j] >= 0.f) ? (vv[j] + 1e-4f) : (vv[j] - 1e-4f);
                float r = __builtin_amdgcn_rcpf(d);
                unsigned short hi = bf16_rne(r);
                hv[j] = hi;
                lv[j] = bf16_rne(r - bf16_to_f(hi));
            }
        } else {
            #pragma unroll
            for (int j = 0; j < 4; ++j) { hv[j] = 0; lv[j] = 0; }
        }
        *reinterpret_cast<i32x2*>(dhi)       = *reinterpret_cast<const i32x2*>(hv);
        *reinterpret_cast<i32x2*>(dhi + 512) = *reinterpret_cast<const i32x2*>(lv);
    }
}

// ---------------- W fragment table prep ----------------
// layout: [c][ks(3)][cfg(16)][part(2)][lane(64)][8 bf16]
__global__ void wfrag_prep(const float* __restrict__ nei_W, unsigned short* __restrict__ wfrag) {
    int e = blockIdx.x;            // ((c*3+ks)*16+cfg)*2+part, 0..575
    int l = threadIdx.x;           // 0..63
    int part = e & 1;
    int cfg = (e >> 1) & 15;
    int ks = (e >> 5) % 3;
    int c = e / 96;
    int col = cfg * 16 + (l & 15);
    unsigned short v[8] __attribute__((aligned(16)));
    #pragma unroll
    for (int j = 0; j < 8; ++j) {
        int k = ks * 32 + ((l >> 4) * 8) + j;
        float w = (k < IN_DIM) ? nei_W[((size_t)c * IN_DIM + k) * EMBED + col] : 0.f;
        unsigned short h = bf16_rne(w);
        if (part == 0) v[j] = h;
        else v[j] = bf16_rne(w - bf16_to_f(h));
    }
    unsigned short* dst = wfrag + ((size_t)e * 64 + l) * 8;
    *reinterpret_cast<i32x4*>(dst) = *reinterpret_cast<const i32x4*>(v);
}

// ---------------- K3: proj[c][m][o] ----------------
__global__ void mode_proj(const float* __restrict__ modes,
                          const float* __restrict__ mode_W,
                          const float* __restrict__ mode_b,
                          float* __restrict__ proj) {
    int cm = blockIdx.x;
    int o = threadIdx.x;
    const float* mv = modes + (size_t)cm * EMBED;
    float acc = mode_b[o];
    #pragma unroll 8
    for (int k = 0; k < EMBED; ++k)
        acc = fmaf(mv[k], mode_W[(size_t)(EMBED + k) * EMBED + o], acc);
    proj[(size_t)cm * EMBED + o] = acc;
}

// ---------------- K4: obs embedding + mode head ----------------
#define BPB 8
__global__ __launch_bounds__(256, 2)
void obs_mode(const float* __restrict__ obs, const int* __restrict__ self_labels,
              const float* __restrict__ obs_W, const float* __restrict__ obs_b,
              const float* __restrict__ mode_W, const float* __restrict__ proj,
              float* __restrict__ out0) {
    int b0 = blockIdx.x * BPB;
    int o = threadIdx.x;
    __shared__ float obs_s[BPB][IN_DIM];
    __shared__ float x_s[BPB][EMBED];
    __shared__ int cls_s[BPB];

    for (int t = threadIdx.x; t < BPB * IN_DIM; t += 256) {
        int bb = t / IN_DIM, k = t % IN_DIM;
        obs_s[bb][k] = obs[(size_t)(b0 + bb) * IN_DIM + k];
    }
    if (threadIdx.x < BPB) cls_s[threadIdx.x] = self_labels[b0 + threadIdx.x];
    __syncthreads();

    int c[BPB];
    float xacc[BPB];
    #pragma unroll
    for (int bb = 0; bb < BPB; ++bb) {
        c[bb] = cls_s[bb];
        xacc[bb] = obs_b[c[bb] * EMBED + o];
    }
    #pragma unroll 4
    for (int k = 0; k < IN_DIM; ++k) {
        #pragma unroll
        for (int bb = 0; bb < BPB; ++bb)
            xacc[bb] = fmaf(obs_s[bb][k],
                            obs_W[(size_t)c[bb] * IN_DIM * EMBED + (size_t)k * EMBED + o],
                            xacc[bb]);
    }
    #pragma unroll
    for (int bb = 0; bb < BPB; ++bb) x_s[bb][o] = xacc[bb];
    __syncthreads();

    float tacc[BPB];
    #pragma unroll
    for (int bb = 0; bb < BPB; ++bb) tacc[bb] = 0.f;
    #pragma unroll 4
    for (int k = 0; k < EMBED; ++k) {
        float wv = mode_W[(size_t)k * EMBED + o];
        #pragma unroll
        for (int bb = 0; bb < BPB; ++bb)
            tacc[bb] = fmaf(x_s[bb][k], wv, tacc[bb]);
    }
    #pragma unroll
    for (int bb = 0; bb < BPB; ++bb) {
        const float* pj = proj + (size_t)c[bb] * NMODES * EMBED;
        float* op = out0 + (size_t)(b0 + bb) * NMODES * EMBED;
        for (int m = 0; m < NMODES; ++m)
            op[m * EMBED + o] = tacc[bb] + pj[m * EMBED + o];
    }
}

// ---------------- K5: MFMA neighbor GEMM — linear frag loads, full-line stores ----
__global__ __launch_bounds__(256, 3)
void nei_gemm2(const unsigned short* __restrict__ packbuf,
               const unsigned short* __restrict__ wfrag,
               const float* __restrict__ nei_b,
               const int* __restrict__ counts, const int* __restrict__ tileoff,
               const int* __restrict__ lists,
               float* __restrict__ out_n) {
    const int b = blockIdx.x;
    const int c = b / (GRIDB / NEXP);          // 128 blocks per class
    const int blk = b - c * (GRIDB / NEXP);
    const int nblk = GRIDB / NEXP;
    const int cnt = counts[c];
    const int to_c = tileoff[c];
    const int ntiles = tileoff[c + 1] - to_c;
    if (blk >= ntiles) return;

    const int t = threadIdx.x;
    const int ch = t >> 6;                     // wave id = col quarter
    const int l = t & 63;
    const int* mylist = lists + (size_t)c * NROWS;

    // B fragments, register-resident (96 VGPR)
    bf16x8 wh[3][4], wl[3][4];
    {
        const unsigned short* wb = wfrag + (size_t)c * 96 * 64 * 8;
        #pragma unroll
        for (int ks = 0; ks < 3; ++ks)
            #pragma unroll
            for (int cf = 0; cf < 4; ++cf) {
                size_t base = ((((size_t)ks * 16 + (ch * 4 + cf)) * 2) * 64 + l) * 8;
                wh[ks][cf] = *reinterpret_cast<const bf16x8*>(wb + base);
                wl[ks][cf] = *reinterpret_cast<const bf16x8*>(wb + base + 64 * 8);
            }
    }
    float bias[4];
    #pragma unroll
    for (int cf = 0; cf < 4; ++cf)
        bias[cf] = nei_b[c * EMBED + (ch * 4 + cf) * 16 + (l & 15)];

    __shared__ float buf[2][TM][EMBED + 4];
    __shared__ int rid_s[2][TM];

    int cur = 0;
    for (int lt = blk; lt < ntiles; lt += nblk) {
        const unsigned short* tb = packbuf + (size_t)(to_c + lt) * TILE_SH;
        if (t < TM) {
            int gi = lt * TM + t;
            rid_s[cur][t] = (gi < cnt) ? mylist[gi] : -1;
        }
        bf16x8 ah[3], al[3];
        #pragma unroll
        for (int ks = 0; ks < 3; ++ks) {
            ah[ks] = *reinterpret_cast<const bf16x8*>(tb + ks * 1024 + l * 8);
            al[ks] = *reinterpret_cast<const bf16x8*>(tb + ks * 1024 + 512 + l * 8);
        }
        f32x4 acc[4];
        #pragma unroll
        for (int cf = 0; cf < 4; ++cf) acc[cf] = (f32x4){0.f, 0.f, 0.f, 0.f};
        #pragma unroll
        for (int ks = 0; ks < 3; ++ks) {
            #pragma unroll
            for (int cf = 0; cf < 4; ++cf) {
                acc[cf] = __builtin_amdgcn_mfma_f32_16x16x32_bf16(ah[ks], wh[ks][cf], acc[cf], 0, 0, 0);
                acc[cf] = __builtin_amdgcn_mfma_f32_16x16x32_bf16(al[ks], wh[ks][cf], acc[cf], 0, 0, 0);
                acc[cf] = __builtin_amdgcn_mfma_f32_16x16x32_bf16(ah[ks], wl[ks][cf], acc[cf], 0, 0, 0);
            }
        }
        // acc -> LDS (row = (l>>4)*4+i, col = ch*64 + cf*16 + (l&15))
        #pragma unroll
        for (int cf = 0; cf < 4; ++cf) {
            int col = ch * 64 + cf * 16 + (l & 15);
            #pragma unroll
            for (int i = 0; i < 4; ++i)
                buf[cur][(l >> 4) * 4 + i][col] = acc[cf][i] + bias[cf];
        }
        __syncthreads();
        // full-line store: thread t -> row t>>4; 4 x float4 segments cover all 256 floats
        {
            int row = t >> 4, seg = t & 15;
            int rid = rid_s[cur][row];
            if (rid >= 0) {
                float* op = out_n + (size_t)rid * EMBED;
                #pragma unroll
                for (int sb = 0; sb < 4; ++sb) {
                    int s4 = (seg + sb * 16) * 4;
                    float4 vv = *reinterpret_cast<const float4*>(&buf[cur][row][s4]);
                    *reinterpret_cast<float4*>(op + s4) = vv;
                }
            }
        }
        cur ^= 1;
    }
}

extern "C" void kernel_launch(void* const* d_in, const int* in_sizes, int n_in,
                              void* d_out, int out_size, void* d_ws, size_t ws_size,
                              hipStream_t stream) {
    const float* obs         = (const float*)d_in[0];
    const float* neis        = (const float*)d_in[1];
    const int*   self_labels = (const int*)d_in[2];
    const int*   nei_labels  = (const int*)d_in[3];
    const float* modes       = (const float*)d_in[4];
    const float* obs_W       = (const float*)d_in[5];
    const float* obs_b       = (const float*)d_in[6];
    const float* nei_W       = (const float*)d_in[7];
    const float* nei_b       = (const float*)d_in[8];
    const float* mode_W      = (const float*)d_in[9];
    const float* mode_b      = (const float*)d_in[10];

    float* out0  = (float*)d_out;
    float* out_n = out0 + (size_t)BATCH * NMODES * EMBED;

    char* ws = (char*)d_ws;
    int* counts  = (int*)ws;                                  // 24 B
    int* tileoff = (int*)(ws + 64);                           // 28 B
    int* lists   = (int*)(ws + 256);                          // 3 MiB
    size_t off = 256 + (size_t)NEXP * NROWS * 4;
    float* proj = (float*)(ws + off);                         // 100 KiB
    off += (size_t)NCLS * NMODES * EMBED * 4;
    unsigned short* wfrag = (unsigned short*)(ws + off);      // 576 KiB
    off += (size_t)NEXP * 96 * 64 * 8 * 2;
    unsigned short* packbuf = (unsigned short*)(ws + off);    // ~51.6 MiB

    hipMemsetAsync(counts, 0, NEXP * sizeof(int), stream);

    bin_rows<<<NROWS / 256, 256, 0, stream>>>(nei_labels, counts, lists);
    scan_tiles<<<1, 1, 0, stream>>>(counts, tileoff);
    pack_tiles<<<NTILES_MAX, 256, 0, stream>>>(neis, counts, tileoff, lists, packbuf);
    wfrag_prep<<<NEXP * 96, 64, 0, stream>>>(nei_W, wfrag);
    mode_proj<<<NCLS * NMODES, 256, 0, stream>>>(modes, mode_W, mode_b, proj);
    obs_mode<<<BATCH / BPB, 256, 0, stream>>>(obs, self_labels, obs_W, obs_b,
                                              mode_W, proj, out0);
    nei_gemm2<<<GRIDB, 256, 0, stream>>>(packbuf, wfrag, nei_b,
                                         counts, tileoff, lists, out_n);
}

// Round 8
// 105.580 us; speedup vs baseline: 1.2318x; 1.2318x over previous
//
#include <hip/hip_runtime.h>

#define BATCH 2048
#define NNEI 64
#define IN_DIM 80
#define EMBED 256
#define NCLS 5
#define NMODES 20
#define NROWS (BATCH * NNEI)   // 131072
#define NEXP (NCLS + 1)        // 6 neighbor experts
#define TM 16                  // rows per MFMA tile
#define GRID2 512              // persistent blocks for nei_gemv (2/CU)

typedef __attribute__((ext_vector_type(8))) short bf16x8;
typedef __attribute__((ext_vector_type(4))) float f32x4;
typedef __attribute__((ext_vector_type(4))) int i32x4;

__device__ inline unsigned short bf16_rne(float f) {
    unsigned u = __builtin_bit_cast(unsigned, f);
    unsigned r = (u + 0x7fffu + ((u >> 16) & 1u)) >> 16;
    return (unsigned short)r;
}
__device__ inline float bf16_to_f(unsigned short h) {
    unsigned u = ((unsigned)h) << 16;
    return __builtin_bit_cast(float, u);
}

// ---------------- K1: bin rows by label (per-class region c*NROWS) ----
__global__ void bin_rows(const int* __restrict__ nei_labels,
                         int* __restrict__ counts, int* __restrict__ lists) {
    __shared__ int lc[NEXP], lb[NEXP];
    int t = threadIdx.x;
    if (t < NEXP) lc[t] = 0;
    __syncthreads();
    int r = blockIdx.x * 256 + t;
    int c = nei_labels[r];
    int lpos = atomicAdd(&lc[c], 1);
    __syncthreads();
    if (t < NEXP) lb[t] = atomicAdd(&counts[t], lc[t]);
    __syncthreads();
    lists[(size_t)c * NROWS + lb[c] + lpos] = r;
}

// ---------------- W fragment table prep ----------------
// layout: [c][ks(3)][cfg(16)][part(2)][lane(64)][8 bf16]
// element j of lane l: k = ks*32 + (l>>4)*8 + j (zero for k>=80), col = cfg*16 + (l&15)
__global__ void wfrag_prep(const float* __restrict__ nei_W, unsigned short* __restrict__ wfrag) {
    int e = blockIdx.x;            // ((c*3+ks)*16+cfg)*2+part, 0..575
    int l = threadIdx.x;           // 0..63
    int part = e & 1;
    int cfg = (e >> 1) & 15;
    int ks = (e >> 5) % 3;
    int c = e / 96;
    int col = cfg * 16 + (l & 15);
    unsigned short v[8] __attribute__((aligned(16)));
    #pragma unroll
    for (int j = 0; j < 8; ++j) {
        int k = ks * 32 + ((l >> 4) * 8) + j;
        float w = (k < IN_DIM) ? nei_W[((size_t)c * IN_DIM + k) * EMBED + col] : 0.f;
        unsigned short h = bf16_rne(w);
        if (part == 0) v[j] = h;
        else v[j] = bf16_rne(w - bf16_to_f(h));
    }
    unsigned short* dst = wfrag + ((size_t)e * 64 + l) * 8;
    *reinterpret_cast<i32x4*>(dst) = *reinterpret_cast<const i32x4*>(v);
}

// ---------------- K2: proj[c][m][o] ----------------
__global__ void mode_proj(const float* __restrict__ modes,
                          const float* __restrict__ mode_W,
                          const float* __restrict__ mode_b,
                          float* __restrict__ proj) {
    int cm = blockIdx.x;
    int o = threadIdx.x;
    const float* mv = modes + (size_t)cm * EMBED;
    float acc = mode_b[o];
    #pragma unroll 8
    for (int k = 0; k < EMBED; ++k)
        acc = fmaf(mv[k], mode_W[(size_t)(EMBED + k) * EMBED + o], acc);
    proj[(size_t)cm * EMBED + o] = acc;
}

// ---------------- K3: obs embedding + mode head ----------------
#define BPB 4
__global__ __launch_bounds__(256, 2)
void obs_mode(const float* __restrict__ obs, const int* __restrict__ self_labels,
              const float* __restrict__ obs_W, const float* __restrict__ obs_b,
              const float* __restrict__ mode_W, const float* __restrict__ proj,
              float* __restrict__ out0) {
    int b0 = blockIdx.x * BPB;
    int o = threadIdx.x;
    __shared__ float obs_s[BPB][IN_DIM];
    __shared__ float x_s[BPB][EMBED];
    __shared__ int cls_s[BPB];

    for (int t = threadIdx.x; t < BPB * IN_DIM; t += 256) {
        int bb = t / IN_DIM, k = t % IN_DIM;
        obs_s[bb][k] = obs[(size_t)(b0 + bb) * IN_DIM + k];
    }
    if (threadIdx.x < BPB) cls_s[threadIdx.x] = self_labels[b0 + threadIdx.x];
    __syncthreads();

    int c[BPB];
    float xacc[BPB];
    #pragma unroll
    for (int bb = 0; bb < BPB; ++bb) {
        c[bb] = cls_s[bb];
        xacc[bb] = obs_b[c[bb] * EMBED + o];
    }
    #pragma unroll 4
    for (int k = 0; k < IN_DIM; ++k) {
        #pragma unroll
        for (int bb = 0; bb < BPB; ++bb)
            xacc[bb] = fmaf(obs_s[bb][k],
                            obs_W[(size_t)c[bb] * IN_DIM * EMBED + (size_t)k * EMBED + o],
                            xacc[bb]);
    }
    #pragma unroll
    for (int bb = 0; bb < BPB; ++bb) x_s[bb][o] = xacc[bb];
    __syncthreads();

    float tacc[BPB];
    #pragma unroll
    for (int bb = 0; bb < BPB; ++bb) tacc[bb] = 0.f;
    #pragma unroll 4
    for (int k = 0; k < EMBED; ++k) {
        float wv = mode_W[(size_t)k * EMBED + o];
        #pragma unroll
        for (int bb = 0; bb < BPB; ++bb)
            tacc[bb] = fmaf(x_s[bb][k], wv, tacc[bb]);
    }
    #pragma unroll
    for (int bb = 0; bb < BPB; ++bb) {
        const float* pj = proj + (size_t)c[bb] * NMODES * EMBED;
        float* op = out0 + (size_t)(b0 + bb) * NMODES * EMBED;
        for (int m = 0; m < NMODES; ++m)
            op[m * EMBED + o] = tacc[bb] + pj[m * EMBED + o];
    }
}

// ---------------- K4: MFMA neighbor GEMM — persistent, weights PINNED in VGPRs ----
// Per class c: out_n[row][o] = nei_b[c][o] + sum_k r[row][k]*nei_W[c][k][o]
// bf16 hi/lo split: r·w ≈ rh·wh + rl·wh + rh·wl
__global__ __launch_bounds__(256, 2)
void nei_gemv_mfma(const float* __restrict__ neis,
                   const unsigned short* __restrict__ wfrag,
                   const float* __restrict__ nei_b,
                   const int* __restrict__ counts,
                   const int* __restrict__ lists,
                   float* __restrict__ out_n) {
    const int b = blockIdx.x;
    const int c = (b * NEXP) / GRID2;                    // contiguous class ranges
    const int cstart = (c * GRID2 + NEXP - 1) / NEXP;
    const int cend = ((c + 1) * GRID2 + NEXP - 1) / NEXP;
    const int blk = b - cstart;
    const int nblk = cend - cstart;
    const int cnt = counts[c];
    const int ntiles = (cnt + TM - 1) / TM;
    if (blk >= ntiles || cnt == 0) return;

    const int ch = threadIdx.x >> 6;   // wave id = col-quarter 0..3
    const int l = threadIdx.x & 63;
    const int* mylist = lists + (size_t)c * NROWS;
    const int kc = (l >> 4) * 8;       // lane's k-chunk base within a 32-k slab

    // --- B fragments: load once, then PIN in registers (defeat load-sinking) ---
    bf16x8 wh[3][4], wl[3][4];
    {
        const unsigned short* wb = wfrag + (size_t)c * 96 * 64 * 8;
        #pragma unroll
        for (int ks = 0; ks < 3; ++ks)
            #pragma unroll
            for (int cf = 0; cf < 4; ++cf) {
                size_t base = ((((size_t)ks * 16 + (ch * 4 + cf)) * 2) * 64 + l) * 8;
                wh[ks][cf] = *reinterpret_cast<const bf16x8*>(wb + base);
                wl[ks][cf] = *reinterpret_cast<const bf16x8*>(wb + base + 64 * 8);
            }
    }
    #pragma unroll
    for (int ks = 0; ks < 3; ++ks)
        #pragma unroll
        for (int cf = 0; cf < 4; ++cf) {
            i32x4 th = __builtin_bit_cast(i32x4, wh[ks][cf]);
            asm volatile("" : "+v"(th));
            wh[ks][cf] = __builtin_bit_cast(bf16x8, th);
            i32x4 tl = __builtin_bit_cast(i32x4, wl[ks][cf]);
            asm volatile("" : "+v"(tl));
            wl[ks][cf] = __builtin_bit_cast(bf16x8, tl);
        }

    float bias[4];
    #pragma unroll
    for (int cf = 0; cf < 4; ++cf) {
        bias[cf] = nei_b[c * EMBED + (ch * 4 + cf) * 16 + (l & 15)];
        asm volatile("" : "+v"(bias[cf]));
    }

#define LOADT(F, R, T) {                                                      \
    int gi_ = (T) * TM + (l & 15);                                            \
    R = mylist[min(gi_, cnt - 1)];                                            \
    const float* bp_ = neis + (size_t)(unsigned)R * IN_DIM;                   \
    _Pragma("unroll")                                                         \
    for (int ks_ = 0; ks_ < 3; ++ks_) {                                       \
        int k0_ = ks_ * 32 + kc;                                              \
        if (k0_ + 8 > IN_DIM) k0_ = 0; /* B frag is zero for k>=80 */         \
        *reinterpret_cast<float4*>(&F[ks_ * 8])     = *reinterpret_cast<const float4*>(bp_ + k0_);     \
        *reinterpret_cast<float4*>(&F[ks_ * 8 + 4]) = *reinterpret_cast<const float4*>(bp_ + k0_ + 4); \
    } }

#define COMPT(F, R, T) {                                                      \
    bf16x8 ah_[3], al_[3];                                                    \
    _Pragma("unroll")                                                         \
    for (int ks_ = 0; ks_ < 3; ++ks_) {                                       \
        _Pragma("unroll")                                                     \
        for (int j_ = 0; j_ < 8; ++j_) {                                      \
            float v_ = F[ks_ * 8 + j_];                                       \
            float d_ = (v_ >= 0.f) ? (v_ + 1e-4f) : (v_ - 1e-4f);             \
            float r_ = __builtin_amdgcn_rcpf(d_);                             \
            unsigned short hi_ = bf16_rne(r_);                                \
            ah_[ks_][j_] = (short)hi_;                                        \
            al_[ks_][j_] = (short)bf16_rne(r_ - bf16_to_f(hi_));              \
        }                                                                     \
    }                                                                         \
    f32x4 acc_[4];                                                            \
    _Pragma("unroll")                                                         \
    for (int cf_ = 0; cf_ < 4; ++cf_) acc_[cf_] = (f32x4){0.f, 0.f, 0.f, 0.f};\
    _Pragma("unroll")                                                         \
    for (int ks_ = 0; ks_ < 3; ++ks_) {                                       \
        _Pragma("unroll")                                                     \
        for (int cf_ = 0; cf_ < 4; ++cf_) {                                   \
            acc_[cf_] = __builtin_amdgcn_mfma_f32_16x16x32_bf16(ah_[ks_], wh[ks_][cf_], acc_[cf_], 0, 0, 0); \
            acc_[cf_] = __builtin_amdgcn_mfma_f32_16x16x32_bf16(al_[ks_], wh[ks_][cf_], acc_[cf_], 0, 0, 0); \
            acc_[cf_] = __builtin_amdgcn_mfma_f32_16x16x32_bf16(ah_[ks_], wl[ks_][cf_], acc_[cf_], 0, 0, 0); \
        }                                                                     \
    }                                                                         \
    int rb_ = (l >> 4) * 4;                                                   \
    _Pragma("unroll")                                                         \
    for (int i_ = 0; i_ < 4; ++i_) {                                          \
        int rid_ = __shfl(R, rb_ + i_);                                       \
        if ((T) * TM + rb_ + i_ < cnt) {                                      \
            float* op_ = out_n + (size_t)(unsigned)rid_ * EMBED + (l & 15);   \
            _Pragma("unroll")                                                 \
            for (int cf_ = 0; cf_ < 4; ++cf_)                                 \
                op_[(ch * 4 + cf_) * 16] = acc_[cf_][i_] + bias[cf_];         \
        }                                                                     \
    } }

    float fA[24], fB[24];
    int ridA, ridB;
    int tile = blk;
    LOADT(fA, ridA, tile)
    while (true) {
        int nt = tile + nblk;
        bool hn = nt < ntiles;
        if (hn) LOADT(fB, ridB, nt)       // prefetch overlaps compute below
        COMPT(fA, ridA, tile)
        if (!hn) break;
        tile = nt;
        nt = tile + nblk;
        hn = nt < ntiles;
        if (hn) LOADT(fA, ridA, nt)
        COMPT(fB, ridB, tile)
        if (!hn) break;
        tile = nt;
    }
#undef LOADT
#undef COMPT
}

extern "C" void kernel_launch(void* const* d_in, const int* in_sizes, int n_in,
                              void* d_out, int out_size, void* d_ws, size_t ws_size,
                              hipStream_t stream) {
    const float* obs         = (const float*)d_in[0];
    const float* neis        = (const float*)d_in[1];
    const int*   self_labels = (const int*)d_in[2];
    const int*   nei_labels  = (const int*)d_in[3];
    const float* modes       = (const float*)d_in[4];
    const float* obs_W       = (const float*)d_in[5];
    const float* obs_b       = (const float*)d_in[6];
    const float* nei_W       = (const float*)d_in[7];
    const float* nei_b       = (const float*)d_in[8];
    const float* mode_W      = (const float*)d_in[9];
    const float* mode_b      = (const float*)d_in[10];

    float* out0  = (float*)d_out;
    float* out_n = out0 + (size_t)BATCH * NMODES * EMBED;

    char* ws = (char*)d_ws;
    int* counts = (int*)ws;                                        // 24 B
    int* lists  = (int*)(ws + 256);                                // 3 MiB
    float* proj = (float*)(ws + 256 + (size_t)NEXP * NROWS * 4);   // 100 KiB
    unsigned short* wfrag = (unsigned short*)(ws + 256 + (size_t)NEXP * NROWS * 4
                                              + (size_t)NCLS * NMODES * EMBED * 4); // 576 KiB

    hipMemsetAsync(counts, 0, NEXP * sizeof(int), stream);

    bin_rows<<<NROWS / 256, 256, 0, stream>>>(nei_labels, counts, lists);
    wfrag_prep<<<NEXP * 96, 64, 0, stream>>>(nei_W, wfrag);
    mode_proj<<<NCLS * NMODES, 256, 0, stream>>>(modes, mode_W, mode_b, proj);
    obs_mode<<<BATCH / BPB, 256, 0, stream>>>(obs, self_labels, obs_W, obs_b,
                                              mode_W, proj, out0);
    nei_gemv_mfma<<<GRID2, 256, 0, stream>>>(neis, wfrag, nei_b,
                                             counts, lists, out_n);
}

// Round 9
// 96.850 us; speedup vs baseline: 1.3428x; 1.0901x over previous
//
#include <hip/hip_runtime.h>

#define BATCH 2048
#define NNEI 64
#define IN_DIM 80
#define EMBED 256
#define NCLS 5
#define NMODES 20
#define NROWS (BATCH * NNEI)   // 131072
#define NEXP (NCLS + 1)        // 6 neighbor experts
#define TM 16                  // rows per MFMA tile
#define GRID2 512              // persistent blocks for nei_gemv (2/CU)
#define MAXT 104               // max tiles per block (covers worst-case skew)

#define NBIN (NROWS / 256)     // 512 bin blocks
#define NWF 144                // wfrag blocks (4 frags each, 576 total)
#define NPRJ (NCLS * NMODES)   // 100 proj blocks

typedef __attribute__((ext_vector_type(8))) short bf16x8;
typedef __attribute__((ext_vector_type(4))) float f32x4;
typedef __attribute__((ext_vector_type(4))) int i32x4;

__device__ inline unsigned short bf16_rne(float f) {
    unsigned u = __builtin_bit_cast(unsigned, f);
    unsigned r = (u + 0x7fffu + ((u >> 16) & 1u)) >> 16;
    return (unsigned short)r;
}
__device__ inline float bf16_to_f(unsigned short h) {
    unsigned u = ((unsigned)h) << 16;
    return __builtin_bit_cast(float, u);
}

// ---------------- K1: fused prep — bin | wfrag | proj by blockIdx range ----
__global__ void prep_all(const int* __restrict__ nei_labels,
                         int* __restrict__ counts, int* __restrict__ lists,
                         const float* __restrict__ nei_W, unsigned short* __restrict__ wfrag,
                         const float* __restrict__ modes, const float* __restrict__ mode_W,
                         const float* __restrict__ mode_b, float* __restrict__ proj) {
    __shared__ int lc[NEXP], lb[NEXP];
    const int b = blockIdx.x;
    const int t = threadIdx.x;

    if (b < NBIN) {
        // ---- bin rows by label (per-class region c*NROWS) ----
        if (t < NEXP) lc[t] = 0;
        __syncthreads();
        int r = b * 256 + t;
        int c = nei_labels[r];
        int lpos = atomicAdd(&lc[c], 1);
        __syncthreads();
        if (t < NEXP) lb[t] = atomicAdd(&counts[t], lc[t]);
        __syncthreads();
        lists[(size_t)c * NROWS + lb[c] + lpos] = r;
    } else if (b < NBIN + NWF) {
        // ---- W fragment table: [c][ks(3)][cfg(16)][part(2)][lane(64)][8 bf16] ----
        int e = (b - NBIN) * 4 + (t >> 6);    // 0..575
        int l = t & 63;
        int part = e & 1;
        int cfg = (e >> 1) & 15;
        int ks = (e >> 5) % 3;
        int c = e / 96;
        int col = cfg * 16 + (l & 15);
        unsigned short v[8] __attribute__((aligned(16)));
        #pragma unroll
        for (int j = 0; j < 8; ++j) {
            int k = ks * 32 + ((l >> 4) * 8) + j;
            float w = (k < IN_DIM) ? nei_W[((size_t)c * IN_DIM + k) * EMBED + col] : 0.f;
            unsigned short h = bf16_rne(w);
            if (part == 0) v[j] = h;
            else v[j] = bf16_rne(w - bf16_to_f(h));
        }
        unsigned short* dst = wfrag + ((size_t)e * 64 + l) * 8;
        *reinterpret_cast<i32x4*>(dst) = *reinterpret_cast<const i32x4*>(v);
    } else {
        // ---- proj[c][m][o] = mode_b[o] + sum_k modes[c,m,k]*mode_W[256+k][o] ----
        int cm = b - (NBIN + NWF);            // 0..99
        int o = t;
        const float* mv = modes + (size_t)cm * EMBED;
        float acc = mode_b[o];
        #pragma unroll 8
        for (int k = 0; k < EMBED; ++k)
            acc = fmaf(mv[k], mode_W[(size_t)(EMBED + k) * EMBED + o], acc);
        proj[(size_t)cm * EMBED + o] = acc;
    }
}

// ---------------- K2: obs embedding + mode head ----------------
#define BPB 4
__global__ __launch_bounds__(256, 2)
void obs_mode(const float* __restrict__ obs, const int* __restrict__ self_labels,
              const float* __restrict__ obs_W, const float* __restrict__ obs_b,
              const float* __restrict__ mode_W, const float* __restrict__ proj,
              float* __restrict__ out0) {
    int b0 = blockIdx.x * BPB;
    int o = threadIdx.x;
    __shared__ float obs_s[BPB][IN_DIM];
    __shared__ float x_s[BPB][EMBED];
    __shared__ int cls_s[BPB];

    for (int t = threadIdx.x; t < BPB * IN_DIM; t += 256) {
        int bb = t / IN_DIM, k = t % IN_DIM;
        obs_s[bb][k] = obs[(size_t)(b0 + bb) * IN_DIM + k];
    }
    if (threadIdx.x < BPB) cls_s[threadIdx.x] = self_labels[b0 + threadIdx.x];
    __syncthreads();

    int c[BPB];
    float xacc[BPB];
    #pragma unroll
    for (int bb = 0; bb < BPB; ++bb) {
        c[bb] = cls_s[bb];
        xacc[bb] = obs_b[c[bb] * EMBED + o];
    }
    #pragma unroll 4
    for (int k = 0; k < IN_DIM; ++k) {
        #pragma unroll
        for (int bb = 0; bb < BPB; ++bb)
            xacc[bb] = fmaf(obs_s[bb][k],
                            obs_W[(size_t)c[bb] * IN_DIM * EMBED + (size_t)k * EMBED + o],
                            xacc[bb]);
    }
    #pragma unroll
    for (int bb = 0; bb < BPB; ++bb) x_s[bb][o] = xacc[bb];
    __syncthreads();

    float tacc[BPB];
    #pragma unroll
    for (int bb = 0; bb < BPB; ++bb) tacc[bb] = 0.f;
    #pragma unroll 4
    for (int k = 0; k < EMBED; ++k) {
        float wv = mode_W[(size_t)k * EMBED + o];
        #pragma unroll
        for (int bb = 0; bb < BPB; ++bb)
            tacc[bb] = fmaf(x_s[bb][k], wv, tacc[bb]);
    }
    #pragma unroll
    for (int bb = 0; bb < BPB; ++bb) {
        const float* pj = proj + (size_t)c[bb] * NMODES * EMBED;
        float* op = out0 + (size_t)(b0 + bb) * NMODES * EMBED;
        for (int m = 0; m < NMODES; ++m)
            op[m * EMBED + o] = tacc[bb] + pj[m * EMBED + o];
    }
}

// ---------------- K3: MFMA neighbor GEMM — LDS rowid cache + depth-2 prefetch ----
// Per class c: out_n[row][o] = nei_b[c][o] + sum_k r[row][k]*nei_W[c][k][o]
// bf16 hi/lo split: r·w ≈ rh·wh + rl·wh + rh·wl
__global__ __launch_bounds__(256, 2)
void nei_gemv_mfma(const float* __restrict__ neis,
                   const unsigned short* __restrict__ wfrag,
                   const float* __restrict__ nei_b,
                   const int* __restrict__ counts,
                   const int* __restrict__ lists,
                   float* __restrict__ out_n) {
    const int b = blockIdx.x;
    const int c = (b * NEXP) / GRID2;                    // contiguous class ranges
    const int cstart = (c * GRID2 + NEXP - 1) / NEXP;
    const int cend = ((c + 1) * GRID2 + NEXP - 1) / NEXP;
    const int blk = b - cstart;
    const int nblk = cend - cstart;
    const int cnt = counts[c];
    const int ntiles = (cnt + TM - 1) / TM;

    __shared__ int rids_s[MAXT * TM];

    if (blk >= ntiles || cnt == 0) return;
    const int nt = min((ntiles - blk + nblk - 1) / nblk, MAXT);

    const int ch = threadIdx.x >> 6;   // wave id = col-quarter 0..3
    const int l = threadIdx.x & 63;
    const int* mylist = lists + (size_t)c * NROWS;
    const int kc = (l >> 4) * 8;       // lane's k-chunk base within a 32-k slab

    // ---- rowid cache: all my tiles' ids into LDS, once ----
    for (int i = threadIdx.x; i < nt * TM; i += 256) {
        int j = i >> 4, r = i & 15;
        int gi = (blk + j * nblk) * TM + r;
        rids_s[i] = mylist[min(gi, cnt - 1)];
    }

    // ---- B fragments: load once, PIN in registers ----
    bf16x8 wh[3][4], wl[3][4];
    {
        const unsigned short* wb = wfrag + (size_t)c * 96 * 64 * 8;
        #pragma unroll
        for (int ks = 0; ks < 3; ++ks)
            #pragma unroll
            for (int cf = 0; cf < 4; ++cf) {
                size_t base = ((((size_t)ks * 16 + (ch * 4 + cf)) * 2) * 64 + l) * 8;
                wh[ks][cf] = *reinterpret_cast<const bf16x8*>(wb + base);
                wl[ks][cf] = *reinterpret_cast<const bf16x8*>(wb + base + 64 * 8);
            }
    }
    #pragma unroll
    for (int ks = 0; ks < 3; ++ks)
        #pragma unroll
        for (int cf = 0; cf < 4; ++cf) {
            i32x4 th = __builtin_bit_cast(i32x4, wh[ks][cf]);
            asm volatile("" : "+v"(th));
            wh[ks][cf] = __builtin_bit_cast(bf16x8, th);
            i32x4 tl = __builtin_bit_cast(i32x4, wl[ks][cf]);
            asm volatile("" : "+v"(tl));
            wl[ks][cf] = __builtin_bit_cast(bf16x8, tl);
        }
    float bias[4];
    #pragma unroll
    for (int cf = 0; cf < 4; ++cf) {
        bias[cf] = nei_b[c * EMBED + (ch * 4 + cf) * 16 + (l & 15)];
        asm volatile("" : "+v"(bias[cf]));
    }
    __syncthreads();   // rid cache ready

#define LOADJ(F, R, J) {                                                      \
    R = rids_s[(J) * TM + (l & 15)];                                          \
    const float* bp_ = neis + (size_t)(unsigned)R * IN_DIM;                   \
    _Pragma("unroll")                                                         \
    for (int ks_ = 0; ks_ < 3; ++ks_) {                                       \
        int k0_ = ks_ * 32 + kc;                                              \
        if (k0_ + 8 > IN_DIM) k0_ = 0; /* B frag is zero for k>=80 */         \
        *reinterpret_cast<float4*>(&F[ks_ * 8])     = *reinterpret_cast<const float4*>(bp_ + k0_);     \
        *reinterpret_cast<float4*>(&F[ks_ * 8 + 4]) = *reinterpret_cast<const float4*>(bp_ + k0_ + 4); \
    } }

#define COMPJ(F, R, J) {                                                      \
    bf16x8 ah_[3], al_[3];                                                    \
    _Pragma("unroll")                                                         \
    for (int ks_ = 0; ks_ < 3; ++ks_) {                                       \
        _Pragma("unroll")                                                     \
        for (int j_ = 0; j_ < 8; ++j_) {                                      \
            float v_ = F[ks_ * 8 + j_];                                       \
            float d_ = (v_ >= 0.f) ? (v_ + 1e-4f) : (v_ - 1e-4f);             \
            float r_ = __builtin_amdgcn_rcpf(d_);                             \
            unsigned short hi_ = bf16_rne(r_);                                \
            ah_[ks_][j_] = (short)hi_;                                        \
            al_[ks_][j_] = (short)bf16_rne(r_ - bf16_to_f(hi_));              \
        }                                                                     \
    }                                                                         \
    f32x4 acc_[4];                                                            \
    _Pragma("unroll")                                                         \
    for (int cf_ = 0; cf_ < 4; ++cf_) acc_[cf_] = (f32x4){0.f, 0.f, 0.f, 0.f};\
    _Pragma("unroll")                                                         \
    for (int ks_ = 0; ks_ < 3; ++ks_) {                                       \
        _Pragma("unroll")                                                     \
        for (int cf_ = 0; cf_ < 4; ++cf_) {                                   \
            acc_[cf_] = __builtin_amdgcn_mfma_f32_16x16x32_bf16(ah_[ks_], wh[ks_][cf_], acc_[cf_], 0, 0, 0); \
            acc_[cf_] = __builtin_amdgcn_mfma_f32_16x16x32_bf16(al_[ks_], wh[ks_][cf_], acc_[cf_], 0, 0, 0); \
            acc_[cf_] = __builtin_amdgcn_mfma_f32_16x16x32_bf16(ah_[ks_], wl[ks_][cf_], acc_[cf_], 0, 0, 0); \
        }                                                                     \
    }                                                                         \
    int rb_ = (l >> 4) * 4;                                                   \
    int tbase_ = (blk + (J) * nblk) * TM;                                     \
    _Pragma("unroll")                                                         \
    for (int i_ = 0; i_ < 4; ++i_) {                                          \
        int rid_ = __shfl(R, rb_ + i_);                                       \
        if (tbase_ + rb_ + i_ < cnt) {                                        \
            float* op_ = out_n + (size_t)(unsigned)rid_ * EMBED + (l & 15);   \
            _Pragma("unroll")                                                 \
            for (int cf_ = 0; cf_ < 4; ++cf_)                                 \
                op_[(ch * 4 + cf_) * 16] = acc_[cf_][i_] + bias[cf_];         \
        }                                                                     \
    } }

    float fA[24], fB[24], fC[24];
    int ridA, ridB, ridC;
    LOADJ(fA, ridA, 0)
    if (nt > 1) LOADJ(fB, ridB, 1)
    int j = 0;
    while (true) {
        if (j + 2 < nt) LOADJ(fC, ridC, j + 2)
        COMPJ(fA, ridA, j)
        if (j + 1 >= nt) break;
        if (j + 3 < nt) LOADJ(fA, ridA, j + 3)
        COMPJ(fB, ridB, j + 1)
        if (j + 2 >= nt) break;
        if (j + 4 < nt) LOADJ(fB, ridB, j + 4)
        COMPJ(fC, ridC, j + 2)
        if (j + 3 >= nt) break;
        j += 3;
    }
#undef LOADJ
#undef COMPJ
}

extern "C" void kernel_launch(void* const* d_in, const int* in_sizes, int n_in,
                              void* d_out, int out_size, void* d_ws, size_t ws_size,
                              hipStream_t stream) {
    const float* obs         = (const float*)d_in[0];
    const float* neis        = (const float*)d_in[1];
    const int*   self_labels = (const int*)d_in[2];
    const int*   nei_labels  = (const int*)d_in[3];
    const float* modes       = (const float*)d_in[4];
    const float* obs_W       = (const float*)d_in[5];
    const float* obs_b       = (const float*)d_in[6];
    const float* nei_W       = (const float*)d_in[7];
    const float* nei_b       = (const float*)d_in[8];
    const float* mode_W      = (const float*)d_in[9];
    const float* mode_b      = (const float*)d_in[10];

    float* out0  = (float*)d_out;
    float* out_n = out0 + (size_t)BATCH * NMODES * EMBED;

    char* ws = (char*)d_ws;
    int* counts = (int*)ws;                                        // 24 B
    int* lists  = (int*)(ws + 256);                                // 3 MiB
    float* proj = (float*)(ws + 256 + (size_t)NEXP * NROWS * 4);   // 100 KiB
    unsigned short* wfrag = (unsigned short*)(ws + 256 + (size_t)NEXP * NROWS * 4
                                              + (size_t)NCLS * NMODES * EMBED * 4); // 576 KiB

    hipMemsetAsync(counts, 0, NEXP * sizeof(int), stream);

    prep_all<<<NBIN + NWF + NPRJ, 256, 0, stream>>>(nei_labels, counts, lists,
                                                    nei_W, wfrag,
                                                    modes, mode_W, mode_b, proj);
    obs_mode<<<BATCH / BPB, 256, 0, stream>>>(obs, self_labels, obs_W, obs_b,
                                              mode_W, proj, out0);
    nei_gemv_mfma<<<GRID2, 256, 0, stream>>>(neis, wfrag, nei_b,
                                             counts, lists, out_n);
}